// Round 6
// baseline (8535.727 us; speedup 1.0000x reference)
//
#include <hip/hip_runtime.h>

// Persistent batched-GRU kernel for MI355X (gfx950), round 15.
// r14 model: interval wall 4515 cyc; LDS pipe is the tallest pole (~2950
// cyc/CU/interval, 65%), and 1536 of that is re-reading LOOP-INVARIANT
// z_j1/n_j1 weight frags from w_lds (16 b128/wave/interval). Round-15:
// move z1/n1 frags for ks 0..2 (6 frags, 24 VGPR) into PERMANENT registers:
//  - w_lds reads 16 -> 10 per wave per interval (-576 LDS cyc/CU/interval)
//  - post-barrier KSTEPs 0-2 (18 MFMAs) depend only on the A-frag read ->
//    deep MFMA issue while the remaining w-reads queue.
// Carried from r14: two-group pipeline (P/Q), diet gate math, bias-preloaded
// accs, cvt_pk publishes, x chunk staging via LDS, lgkm-only barrier.

#define B_TOTAL 16384
#define T_LEN   1024
#define GRPROWS 16
#define M_ROWS  32
#define NBLOCKS (B_TOTAL / M_ROWS)      // 512 blocks; 2 sequential per CU
#define NTHREADS 512                    // 8 waves
#define LDSW    264                     // h row stride in shorts
#define TCH     32                      // x chunk length (t steps)
#define NCH     (T_LEN / TCH)           // 32
#define XSTR    36                      // x_buf t-row stride in floats

typedef short short8 __attribute__((ext_vector_type(8)));
typedef float f32x4  __attribute__((ext_vector_type(4)));

__device__ unsigned short g_wsw[196608];   // swizzled, PRE-SCALED bf16 W_hh

__device__ __forceinline__ unsigned short f2b(float f) {
  unsigned u = __builtin_bit_cast(unsigned, f);
  u += 0x7fffu + ((u >> 16) & 1u);
  return (unsigned short)(u >> 16);
}
__device__ __forceinline__ unsigned cvt_pk_bf16(float lo, float hi) {
  unsigned r;
  asm("v_cvt_pk_bf16_f32 %0, %1, %2" : "=v"(r) : "v"(lo), "v"(hi));
  return r;
}
// sum over a 16-lane DPP row; result valid in the LAST lane (r16==15)
__device__ __forceinline__ float dpp_red16(float v) {
  int x = __builtin_bit_cast(int, v);
  v += __builtin_bit_cast(float, __builtin_amdgcn_update_dpp(0, x, 0x118, 0xF, 0xF, true)); // row_shr:8
  x = __builtin_bit_cast(int, v);
  v += __builtin_bit_cast(float, __builtin_amdgcn_update_dpp(0, x, 0x114, 0xF, 0xF, true)); // row_shr:4
  x = __builtin_bit_cast(int, v);
  v += __builtin_bit_cast(float, __builtin_amdgcn_update_dpp(0, x, 0x112, 0xF, 0xF, true)); // row_shr:2
  x = __builtin_bit_cast(int, v);
  v += __builtin_bit_cast(float, __builtin_amdgcn_update_dpp(0, x, 0x111, 0xF, 0xF, true)); // row_shr:1
  return v;
}
// barrier draining LDS only (no vmcnt(0): global stores stay in flight)
__device__ __forceinline__ void barrier_lgkm() {
  asm volatile("s_waitcnt lgkmcnt(0)\n\ts_barrier" ::: "memory");
}

// Swizzle W_hh (768x256 f32 row-major) into fragment-major bf16, PRE-SCALED:
// rows 0..511 (r,z) * -log2e ; rows 512..767 (n) * 2*log2e.
__global__ void prep_w(const float* __restrict__ w_hh) {
  int tid  = blockIdx.x * 256 + threadIdx.x;     // 196608 total
  int e    = tid & 7;
  int lane = (tid >> 3) & 63;
  int ks   = (tid >> 9) & 7;
  int nt   = tid >> 12;
  int row  = nt * 16 + (lane & 15);
  int col  = ks * 32 + (lane >> 4) * 8 + e;
  float s  = (row < 512) ? -1.44269504f : 2.88539008f;
  g_wsw[tid] = f2b(w_hh[row * 256 + col] * s);
}

#define MF(A, B, C) __builtin_amdgcn_mfma_f32_16x16x32_bf16((A), (B), (C), 0, 0, 0)

// K-step, ks 0..2: z1/n1 from PERMANENT registers (wz1p/wn1p)
#define KSTEPR(P, AR, KS, EXTRA)  {                                            \
    short8 a_  = *(const short8*)((AR) + (KS)*32);                             \
    P##00 = MF(a_, wrr0[KS], P##00);                                           \
    P##01 = MF(a_, wrr1[KS], P##01);                                           \
    P##10 = MF(a_, wrz0[KS], P##10);                                           \
    P##11 = MF(a_, wz1p[KS], P##11);                                           \
    P##20 = MF(a_, wrn0[KS], P##20);                                           \
    P##21 = MF(a_, wn1p[KS], P##21);                                           \
    EXTRA                                                                      \
  }
// K-step, ks 3..7: z1/n1 from LDS
#define KSTEPL(P, AR, KS, EXTRA)  {                                            \
    short8 a_  = *(const short8*)((AR) + (KS)*32);                             \
    short8 z1_ = *(const short8*)&w_lds[wz1b + (KS)*512];                      \
    short8 n1_ = *(const short8*)&w_lds[wn1b + (KS)*512];                      \
    P##00 = MF(a_, wrr0[KS], P##00);                                           \
    P##01 = MF(a_, wrr1[KS], P##01);                                           \
    P##10 = MF(a_, wrz0[KS], P##10);                                           \
    P##11 = MF(a_, z1_,      P##11);                                           \
    P##20 = MF(a_, wrn0[KS], P##20);                                           \
    P##21 = MF(a_, n1_,      P##21);                                           \
    EXTRA                                                                      \
  }

// one gate element, DIET math (accs carry fused scaled biases).
#define GEL(AC, HR, XV, VO, J, I) {                                            \
    float t_r = __builtin_fmaf(XV[I], swr[J], AC##0##J[I]);                    \
    float rg_ = __builtin_amdgcn_rcpf(1.0f + __builtin_amdgcn_exp2f(t_r));     \
    float t_z = __builtin_fmaf(XV[I], swz[J], AC##1##J[I]);                    \
    float zg_ = __builtin_amdgcn_rcpf(1.0f + __builtin_amdgcn_exp2f(t_z));     \
    float t_n = __builtin_fmaf(XV[I], swn[J], sbni[J]);                        \
    float yn_ = __builtin_fmaf(rg_, AC##2##J[I], t_n);                         \
    float rn_ = __builtin_amdgcn_rcpf(1.0f + __builtin_amdgcn_exp2f(yn_));     \
    float ng_ = __builtin_fmaf(-2.0f, rn_, 1.0f);                              \
    float hn_ = __builtin_fmaf(zg_, HR[J][I] - ng_, ng_);                      \
    HR[J][I] = hn_;                                                            \
    VO[I] += fmaxf(hn_, 0.0f)*wo[J];                                           \
  }

// publish rows (I0, I0+1) of column c(J) for group HG as a packed bf16 pair
#define PUBP(HR, HG, J, I0) {                                                  \
    unsigned pk_ = cvt_pk_bf16(HR[J][I0], HR[J][(I0)+1]);                      \
    h_lds[HG][hwb[J] + (I0)*LDSW]     = (unsigned short)pk_;                   \
    h_lds[HG][hwb[J] + ((I0)+1)*LDSW] = (unsigned short)(pk_ >> 16);           \
  }

#define VORED(VO, G, S) {                                                      \
    _Pragma("unroll") for (int i_ = 0; i_ < 4; ++i_) VO[i_] = dpp_red16(VO[i_]); \
    if (r16 == 15) {                                                           \
      _Pragma("unroll") for (int i_ = 0; i_ < 4; ++i_)                         \
        op[G][(S)&1][w][q*4 + i_] = VO[i_];                                    \
    } }

// finalize out(G, S): 16 threads starting at TLO sum 8 wave partials + store
#define FIN(G, S, TLO)                                                         \
  if (tid >= (TLO) && tid < (TLO) + 16) {                                      \
    float o_ = bo;                                                             \
    _Pragma("unroll") for (int ww_ = 0; ww_ < 8; ++ww_)                        \
      o_ += op[G][(S)&1][ww_][tid - (TLO)];                                    \
    out[(base + (G)*GRPROWS + (tid - (TLO)))*T_LEN + (S)] = o_;                \
  }

// acc init: fused scaled biases (r in acc0, z in acc1, n-hh in acc2)
#define ACCB(P) {                                                              \
    P##00 = (f32x4){sbr[0],sbr[0],sbr[0],sbr[0]};                              \
    P##01 = (f32x4){sbr[1],sbr[1],sbr[1],sbr[1]};                              \
    P##10 = (f32x4){sbz[0],sbz[0],sbz[0],sbz[0]};                              \
    P##11 = (f32x4){sbz[1],sbz[1],sbz[1],sbz[1]};                              \
    P##20 = (f32x4){sbnh[0],sbnh[0],sbnh[0],sbnh[0]};                          \
    P##21 = (f32x4){sbnh[1],sbnh[1],sbnh[1],sbnh[1]};                          \
  }

// broadcast read of 4 x values for group G from x_buf (conflict-free)
#define XREAD(XV, G, XP, TR)                                                   \
  XV = *(const f32x4*)&x_buf[XP][(TR)*XSTR + (G)*GRPROWS + q*4];

__global__ __launch_bounds__(NTHREADS, 2) void gru_kernel(
    const float* __restrict__ x,
    const float* __restrict__ w_ih,
    const float* __restrict__ b_ih,
    const float* __restrict__ b_hh,
    const float* __restrict__ w_out,
    const float* __restrict__ b_out,
    float* __restrict__ out)
{
  __shared__ unsigned short h_lds[2][GRPROWS * LDSW];  // [group], 16.5 KB
  __shared__ unsigned short w_lds[16 * 8 * 512];       // z_j1/n_j1 frags, 128 KB
  __shared__ float op[2][2][8][GRPROWS];               // [group][phase][wave][row], 2 KB
  __shared__ float x_buf[2][TCH * XSTR];               // x chunks [t][row 0..31], 9.2 KB

  const int tid  = threadIdx.x;
  const int w    = tid >> 6;        // wave 0..7
  const int lane = tid & 63;
  const int r16  = lane & 15;
  const int q    = lane >> 4;
  const long base = (long)blockIdx.x * M_ROWS;

  for (int i = tid; i < 2 * GRPROWS * LDSW; i += NTHREADS) h_lds[0][i] = 0;  // h0 = 0 (both groups)

  // ---- stage z_j1 (gsel 0) and n_j1 (gsel 1) frags into LDS ----
  const int wz1b = ((w*2 + 0)*8)*512 + lane*8;
  const int wn1b = ((w*2 + 1)*8)*512 + lane*8;
#pragma unroll
  for (int gsel = 0; gsel < 2; ++gsel)
#pragma unroll
    for (int ks = 0; ks < 8; ++ks)
      *(short8*)&w_lds[((w*2 + gsel)*8 + ks)*512 + lane*8] =
        *(const short8*)&g_wsw[((((gsel + 1)*16 + w*2 + 1)*8 + ks)*64 + lane)*8];

  // ---- register-resident frags: r_j0, r_j1, z_j0, n_j0 (128 VGPR) ----
  short8 wrr0[8], wrr1[8], wrz0[8], wrn0[8];
#pragma unroll
  for (int ks = 0; ks < 8; ++ks) {
    wrr0[ks] = *(const short8*)&g_wsw[(((0*16 + w*2 + 0)*8 + ks)*64 + lane)*8];
    wrr1[ks] = *(const short8*)&g_wsw[(((0*16 + w*2 + 1)*8 + ks)*64 + lane)*8];
    wrz0[ks] = *(const short8*)&g_wsw[(((1*16 + w*2 + 0)*8 + ks)*64 + lane)*8];
    wrn0[ks] = *(const short8*)&g_wsw[(((2*16 + w*2 + 0)*8 + ks)*64 + lane)*8];
  }
  // ---- NEW r15: permanent z_j1/n_j1 frags for ks 0..2 (24 VGPR) ----
  short8 wz1p[3], wn1p[3];
#pragma unroll
  for (int ks = 0; ks < 3; ++ks) {
    wz1p[ks] = *(const short8*)&g_wsw[(((1*16 + w*2 + 1)*8 + ks)*64 + lane)*8];
    wn1p[ks] = *(const short8*)&g_wsw[(((2*16 + w*2 + 1)*8 + ks)*64 + lane)*8];
  }

  // per-lane constants for cols c(j) = w*32 + j*16 + r16, pre-scaled:
  // r,z: -log2e ; n: +2*log2e
  const float C1 = 1.44269504f;
  float swr[2], swz[2], swn[2], sbr[2], sbz[2], sbni[2], sbnh[2], wo[2];
  int hwb[2];
#pragma unroll
  for (int j = 0; j < 2; ++j) {
    int c = w*32 + j*16 + r16;
    hwb[j]   = (q*4)*LDSW + c;
    swr[j]   = -C1 * w_ih[c];
    swz[j]   = -C1 * w_ih[256 + c];
    swn[j]   = 2.0f * C1 * w_ih[512 + c];
    sbr[j]   = -C1 * (b_ih[c]       + b_hh[c]);
    sbz[j]   = -C1 * (b_ih[256 + c] + b_hh[256 + c]);
    sbni[j]  = 2.0f * C1 * b_ih[512 + c];
    sbnh[j]  = 2.0f * C1 * b_hh[512 + c];
    wo[j]    = w_out[c];
  }
  const float bo = b_out[0];
  const f32x4 zero4 = {0.f, 0.f, 0.f, 0.f};

  float hP[2][4], hQ[2][4];        // f32 h carry, both groups
#pragma unroll
  for (int j = 0; j < 2; ++j)
#pragma unroll
    for (int i = 0; i < 4; ++i) { hP[j][i] = 0.0f; hQ[j][i] = 0.0f; }

  const unsigned short* arP = &h_lds[0][r16*LDSW + q*8];
  const unsigned short* arQ = &h_lds[1][r16*LDSW + q*8];

  // x staging indices: thread -> (row = tid>>5 in 0..15, t-slot = tid&31)
  const int xrow = tid >> 5;
  const int xts  = tid & 31;

  // prefill x chunk 0 (both groups; coalesced 32-wide per row)
  x_buf[0][xts*XSTR + xrow]           = x[(base + xrow)*T_LEN + xts];
  x_buf[0][xts*XSTR + GRPROWS + xrow] = x[(base + GRPROWS + xrow)*T_LEN + xts];

  // acc sets: aP## built in A-intervals / consumed in B; aQ## vice versa
  f32x4 aP00, aP01, aP10, aP11, aP20, aP21;
  f32x4 aQ00, aQ01, aQ10, aQ11, aQ20, aQ21;

  barrier_lgkm();   // h zeros + w_lds + x chunk 0 staged

  // ---- pre-loop interval A0: MFMA(P, 0) only ----
  {
    ACCB(aP)
    KSTEPR(aP, arP, 0, ) KSTEPR(aP, arP, 1, ) KSTEPR(aP, arP, 2, )
    KSTEPL(aP, arP, 3, ) KSTEPL(aP, arP, 4, ) KSTEPL(aP, arP, 5, )
    KSTEPL(aP, arP, 6, ) KSTEPL(aP, arP, 7, )
    barrier_lgkm();
  }

#pragma unroll 1
  for (int s = 0; s < T_LEN - 1; ++s) {     // s = 0..1022
    const int tr = s & (TCH - 1);
    const int tc = s >> 5;
    const int xp = tc & 1;
    const int refill = (tr == 1) && (tc + 1 < NCH);

    // ======== interval B(s): MFMA(Q,s) + gates(P,s) + fin(P,s-1) ========
    {
      // x refill: issue coalesced loads NOW, ds_write at interval end
      float xa, xb;
      if (refill) {
        const long t2 = (long)(tc + 1)*TCH + xts;
        xa = x[(base + xrow)*T_LEN + t2];
        xb = x[(base + GRPROWS + xrow)*T_LEN + t2];
      }
      f32x4 xvP; XREAD(xvP, 0, xp, tr)
      if (s > 0) { FIN(0, s-1, 0) }
      ACCB(aQ)
      f32x4 voP = zero4;
      KSTEPR(aQ, arQ, 0, GEL(aP, hP, xvP, voP, 0, 0))
      KSTEPR(aQ, arQ, 1, GEL(aP, hP, xvP, voP, 0, 1) PUBP(hP, 0, 0, 0))
      KSTEPR(aQ, arQ, 2, GEL(aP, hP, xvP, voP, 0, 2))
      KSTEPL(aQ, arQ, 3, GEL(aP, hP, xvP, voP, 0, 3) PUBP(hP, 0, 0, 2))
      KSTEPL(aQ, arQ, 4, GEL(aP, hP, xvP, voP, 1, 0))
      KSTEPL(aQ, arQ, 5, GEL(aP, hP, xvP, voP, 1, 1) PUBP(hP, 0, 1, 0))
      KSTEPL(aQ, arQ, 6, GEL(aP, hP, xvP, voP, 1, 2))
      KSTEPL(aQ, arQ, 7, GEL(aP, hP, xvP, voP, 1, 3) PUBP(hP, 0, 1, 2))
      VORED(voP, 0, s)
      if (refill) {
        x_buf[xp ^ 1][xts*XSTR + xrow]           = xa;
        x_buf[xp ^ 1][xts*XSTR + GRPROWS + xrow] = xb;
      }
      barrier_lgkm();
    }
    // ======== interval A(s+1): MFMA(P,s+1) + gates(Q,s) + fin(Q,s-1) ========
    {
      f32x4 xvQ; XREAD(xvQ, 1, xp, tr)
      if (s > 0) { FIN(1, s-1, 64) }
      ACCB(aP)
      f32x4 voQ = zero4;
      KSTEPR(aP, arP, 0, GEL(aQ, hQ, xvQ, voQ, 0, 0))
      KSTEPR(aP, arP, 1, GEL(aQ, hQ, xvQ, voQ, 0, 1) PUBP(hQ, 1, 0, 0))
      KSTEPR(aP, arP, 2, GEL(aQ, hQ, xvQ, voQ, 0, 2))
      KSTEPL(aP, arP, 3, GEL(aQ, hQ, xvQ, voQ, 0, 3) PUBP(hQ, 1, 0, 2))
      KSTEPL(aP, arP, 4, GEL(aQ, hQ, xvQ, voQ, 1, 0))
      KSTEPL(aP, arP, 5, GEL(aQ, hQ, xvQ, voQ, 1, 1) PUBP(hQ, 1, 1, 0))
      KSTEPL(aP, arP, 6, GEL(aQ, hQ, xvQ, voQ, 1, 2))
      KSTEPL(aP, arP, 7, GEL(aQ, hQ, xvQ, voQ, 1, 3) PUBP(hQ, 1, 1, 2))
      VORED(voQ, 1, s)
      barrier_lgkm();
    }
  }

  // ======== interval B(1023): MFMA(Q,1023) + gates(P,1023) + fin(P,1022) ========
  {
    const int s = T_LEN - 1;                 // tr=31, tc=31, xp=1
    f32x4 xvP; XREAD(xvP, 0, 1, TCH - 1)
    FIN(0, s-1, 0)
    ACCB(aQ)
    f32x4 voP = zero4;
    KSTEPR(aQ, arQ, 0, GEL(aP, hP, xvP, voP, 0, 0))
    KSTEPR(aQ, arQ, 1, GEL(aP, hP, xvP, voP, 0, 1) PUBP(hP, 0, 0, 0))
    KSTEPR(aQ, arQ, 2, GEL(aP, hP, xvP, voP, 0, 2))
    KSTEPL(aQ, arQ, 3, GEL(aP, hP, xvP, voP, 0, 3) PUBP(hP, 0, 0, 2))
    KSTEPL(aQ, arQ, 4, GEL(aP, hP, xvP, voP, 1, 0))
    KSTEPL(aQ, arQ, 5, GEL(aP, hP, xvP, voP, 1, 1) PUBP(hP, 0, 1, 0))
    KSTEPL(aQ, arQ, 6, GEL(aP, hP, xvP, voP, 1, 2))
    KSTEPL(aQ, arQ, 7, GEL(aP, hP, xvP, voP, 1, 3) PUBP(hP, 0, 1, 2))
    VORED(voP, 0, s)
    barrier_lgkm();
  }
  // ======== epilogue interval: gates(Q,1023) + fin(Q,1022) ========
  {
    const int s = T_LEN - 1;
    f32x4 xvQ; XREAD(xvQ, 1, 1, TCH - 1)
    FIN(1, s-1, 64)
    f32x4 voQ = zero4;
    GEL(aQ, hQ, xvQ, voQ, 0, 0)
    GEL(aQ, hQ, xvQ, voQ, 0, 1)
    GEL(aQ, hQ, xvQ, voQ, 0, 2)
    GEL(aQ, hQ, xvQ, voQ, 0, 3)
    GEL(aQ, hQ, xvQ, voQ, 1, 0)
    GEL(aQ, hQ, xvQ, voQ, 1, 1)
    GEL(aQ, hQ, xvQ, voQ, 1, 2)
    GEL(aQ, hQ, xvQ, voQ, 1, 3)
    VORED(voQ, 1, s)
    barrier_lgkm();
  }
  // ======== final finalizes: (P,1023) and (Q,1023) ========
  FIN(0, T_LEN - 1, 0)
  FIN(1, T_LEN - 1, 64)
}

extern "C" void kernel_launch(void* const* d_in, const int* in_sizes, int n_in,
                              void* d_out, int out_size, void* d_ws, size_t ws_size,
                              hipStream_t stream) {
  const float* x     = (const float*)d_in[0];
  const float* w_ih  = (const float*)d_in[1];
  const float* w_hh  = (const float*)d_in[2];
  const float* b_ih  = (const float*)d_in[3];
  const float* b_hh  = (const float*)d_in[4];
  const float* w_out = (const float*)d_in[5];
  const float* b_out = (const float*)d_in[6];
  float* out = (float*)d_out;

  prep_w<<<768, 256, 0, stream>>>(w_hh);
  gru_kernel<<<NBLOCKS, NTHREADS, 0, stream>>>(x, w_ih, b_ih, b_hh, w_out, b_out, out);
}

// Round 8
// 8233.511 us; speedup vs baseline: 1.0367x; 1.0367x over previous
//
#include <hip/hip_runtime.h>

// Persistent batched-GRU kernel for MI355X (gfx950), round 16 (resubmit r17;
// r16 bench was a GPUAcquisitionTimeout, kernel never ran).
// r15 post-mortem: +24 PERMANENT weight VGPRs spilled (WRITE_SIZE 214->890MB,
// dur 8536us) -> register margin over r14 is <24; VGPR_Count readout is
// granule-clamped, WRITE_SIZE is the spill sentinel. This round: revert to
// r14 (7706us best) + two zero/low-risk critical-path fixes:
//  (1) TRANSIENT cross-barrier prefetch of z1/n1 frags for ks=0,1 (16 VGPR,
//      live only interval-end -> KSTEP1, dead at mid-interval pressure peak):
//      first 12 MFMAs after each barrier wait only on the A-frag read instead
//      of queuing behind ~24 block-wide ds_reads. The "memory" clobber on the
//      barrier asm prevents LICM from making these permanent (r15's mistake).
//  (2) rotating FIN owner (B: waves 0,2,4,6; A: 1,3,5,7): spreads FIN's 8
//      extra LDS reads + global store so the same wave isn't the barrier
//      straggler every interval.
// Carried from r14: two-group pipeline (P/Q), diet gate math, bias-preloaded
// accs, cvt_pk publishes, x chunk staging via LDS, lgkm-only barrier.

#define B_TOTAL 16384
#define T_LEN   1024
#define GRPROWS 16
#define M_ROWS  32
#define NBLOCKS (B_TOTAL / M_ROWS)      // 512 blocks; 2 sequential per CU
#define NTHREADS 512                    // 8 waves
#define LDSW    264                     // h row stride in shorts
#define TCH     32                      // x chunk length (t steps)
#define NCH     (T_LEN / TCH)           // 32
#define XSTR    36                      // x_buf t-row stride in floats

typedef short short8 __attribute__((ext_vector_type(8)));
typedef float f32x4  __attribute__((ext_vector_type(4)));

__device__ unsigned short g_wsw[196608];   // swizzled, PRE-SCALED bf16 W_hh

__device__ __forceinline__ unsigned short f2b(float f) {
  unsigned u = __builtin_bit_cast(unsigned, f);
  u += 0x7fffu + ((u >> 16) & 1u);
  return (unsigned short)(u >> 16);
}
__device__ __forceinline__ unsigned cvt_pk_bf16(float lo, float hi) {
  unsigned r;
  asm("v_cvt_pk_bf16_f32 %0, %1, %2" : "=v"(r) : "v"(lo), "v"(hi));
  return r;
}
// sum over a 16-lane DPP row; result valid in the LAST lane (r16==15)
__device__ __forceinline__ float dpp_red16(float v) {
  int x = __builtin_bit_cast(int, v);
  v += __builtin_bit_cast(float, __builtin_amdgcn_update_dpp(0, x, 0x118, 0xF, 0xF, true)); // row_shr:8
  x = __builtin_bit_cast(int, v);
  v += __builtin_bit_cast(float, __builtin_amdgcn_update_dpp(0, x, 0x114, 0xF, 0xF, true)); // row_shr:4
  x = __builtin_bit_cast(int, v);
  v += __builtin_bit_cast(float, __builtin_amdgcn_update_dpp(0, x, 0x112, 0xF, 0xF, true)); // row_shr:2
  x = __builtin_bit_cast(int, v);
  v += __builtin_bit_cast(float, __builtin_amdgcn_update_dpp(0, x, 0x111, 0xF, 0xF, true)); // row_shr:1
  return v;
}
// barrier draining LDS only (no vmcnt(0): global stores stay in flight)
__device__ __forceinline__ void barrier_lgkm() {
  asm volatile("s_waitcnt lgkmcnt(0)\n\ts_barrier" ::: "memory");
}

// Swizzle W_hh (768x256 f32 row-major) into fragment-major bf16, PRE-SCALED:
// rows 0..511 (r,z) * -log2e ; rows 512..767 (n) * 2*log2e.
__global__ void prep_w(const float* __restrict__ w_hh) {
  int tid  = blockIdx.x * 256 + threadIdx.x;     // 196608 total
  int e    = tid & 7;
  int lane = (tid >> 3) & 63;
  int ks   = (tid >> 9) & 7;
  int nt   = tid >> 12;
  int row  = nt * 16 + (lane & 15);
  int col  = ks * 32 + (lane >> 4) * 8 + e;
  float s  = (row < 512) ? -1.44269504f : 2.88539008f;
  g_wsw[tid] = f2b(w_hh[row * 256 + col] * s);
}

#define MF(A, B, C) __builtin_amdgcn_mfma_f32_16x16x32_bf16((A), (B), (C), 0, 0, 0)

// K-step with PREFETCHED z1/n1 register frags (ks 0,1)
#define KSTEPP(P, AR, KS, ZR, NR, EXTRA)  {                                    \
    short8 a_  = *(const short8*)((AR) + (KS)*32);                             \
    P##00 = MF(a_, wrr0[KS], P##00);                                           \
    P##01 = MF(a_, wrr1[KS], P##01);                                           \
    P##10 = MF(a_, wrz0[KS], P##10);                                           \
    P##11 = MF(a_, ZR,       P##11);                                           \
    P##20 = MF(a_, wrn0[KS], P##20);                                           \
    P##21 = MF(a_, NR,       P##21);                                           \
    EXTRA                                                                      \
  }
// K-step with z1/n1 from LDS (ks 2..7)
#define KSTEP(P, AR, KS, EXTRA)  {                                             \
    short8 a_  = *(const short8*)((AR) + (KS)*32);                             \
    short8 z1_ = *(const short8*)&w_lds[wz1b + (KS)*512];                      \
    short8 n1_ = *(const short8*)&w_lds[wn1b + (KS)*512];                      \
    P##00 = MF(a_, wrr0[KS], P##00);                                           \
    P##01 = MF(a_, wrr1[KS], P##01);                                           \
    P##10 = MF(a_, wrz0[KS], P##10);                                           \
    P##11 = MF(a_, z1_,      P##11);                                           \
    P##20 = MF(a_, wrn0[KS], P##20);                                           \
    P##21 = MF(a_, n1_,      P##21);                                           \
    EXTRA                                                                      \
  }

// reload the prefetch frags for the NEXT interval (issued before the barrier;
// values stay valid in regs across it, liveness ends at next KSTEPP1)
#define WPREF {                                                                \
    pz0 = *(const short8*)&w_lds[wz1b];                                        \
    pn0 = *(const short8*)&w_lds[wn1b];                                        \
    pz1 = *(const short8*)&w_lds[wz1b + 512];                                  \
    pn1 = *(const short8*)&w_lds[wn1b + 512];                                  \
  }

// one gate element, DIET math (accs carry fused scaled biases).
#define GEL(AC, HR, XV, VO, J, I) {                                            \
    float t_r = __builtin_fmaf(XV[I], swr[J], AC##0##J[I]);                    \
    float rg_ = __builtin_amdgcn_rcpf(1.0f + __builtin_amdgcn_exp2f(t_r));     \
    float t_z = __builtin_fmaf(XV[I], swz[J], AC##1##J[I]);                    \
    float zg_ = __builtin_amdgcn_rcpf(1.0f + __builtin_amdgcn_exp2f(t_z));     \
    float t_n = __builtin_fmaf(XV[I], swn[J], sbni[J]);                        \
    float yn_ = __builtin_fmaf(rg_, AC##2##J[I], t_n);                         \
    float rn_ = __builtin_amdgcn_rcpf(1.0f + __builtin_amdgcn_exp2f(yn_));     \
    float ng_ = __builtin_fmaf(-2.0f, rn_, 1.0f);                              \
    float hn_ = __builtin_fmaf(zg_, HR[J][I] - ng_, ng_);                      \
    HR[J][I] = hn_;                                                            \
    VO[I] += fmaxf(hn_, 0.0f)*wo[J];                                           \
  }

// publish rows (I0, I0+1) of column c(J) for group HG as a packed bf16 pair
#define PUBP(HR, HG, J, I0) {                                                  \
    unsigned pk_ = cvt_pk_bf16(HR[J][I0], HR[J][(I0)+1]);                      \
    h_lds[HG][hwb[J] + (I0)*LDSW]     = (unsigned short)pk_;                   \
    h_lds[HG][hwb[J] + ((I0)+1)*LDSW] = (unsigned short)(pk_ >> 16);           \
  }

#define VORED(VO, G, S) {                                                      \
    _Pragma("unroll") for (int i_ = 0; i_ < 4; ++i_) VO[i_] = dpp_red16(VO[i_]); \
    if (r16 == 15) {                                                           \
      _Pragma("unroll") for (int i_ = 0; i_ < 4; ++i_)                         \
        op[G][(S)&1][w][q*4 + i_] = VO[i_];                                    \
    } }

// finalize out(G, S): 16 threads starting at TLO sum 8 wave partials + store
#define FIN(G, S, TLO)                                                         \
  if (tid >= (TLO) && tid < (TLO) + 16) {                                      \
    float o_ = bo;                                                             \
    _Pragma("unroll") for (int ww_ = 0; ww_ < 8; ++ww_)                        \
      o_ += op[G][(S)&1][ww_][tid - (TLO)];                                    \
    out[(base + (G)*GRPROWS + (tid - (TLO)))*T_LEN + (S)] = o_;                \
  }

// acc init: fused scaled biases (r in acc0, z in acc1, n-hh in acc2)
#define ACCB(P) {                                                              \
    P##00 = (f32x4){sbr[0],sbr[0],sbr[0],sbr[0]};                              \
    P##01 = (f32x4){sbr[1],sbr[1],sbr[1],sbr[1]};                              \
    P##10 = (f32x4){sbz[0],sbz[0],sbz[0],sbz[0]};                              \
    P##11 = (f32x4){sbz[1],sbz[1],sbz[1],sbz[1]};                              \
    P##20 = (f32x4){sbnh[0],sbnh[0],sbnh[0],sbnh[0]};                          \
    P##21 = (f32x4){sbnh[1],sbnh[1],sbnh[1],sbnh[1]};                          \
  }

// broadcast read of 4 x values for group G from x_buf (conflict-free)
#define XREAD(XV, G, XP, TR)                                                   \
  XV = *(const f32x4*)&x_buf[XP][(TR)*XSTR + (G)*GRPROWS + q*4];

__global__ __launch_bounds__(NTHREADS, 2) void gru_kernel(
    const float* __restrict__ x,
    const float* __restrict__ w_ih,
    const float* __restrict__ b_ih,
    const float* __restrict__ b_hh,
    const float* __restrict__ w_out,
    const float* __restrict__ b_out,
    float* __restrict__ out)
{
  __shared__ unsigned short h_lds[2][GRPROWS * LDSW];  // [group], 16.5 KB
  __shared__ unsigned short w_lds[16 * 8 * 512];       // z_j1/n_j1 frags, 128 KB
  __shared__ float op[2][2][8][GRPROWS];               // [group][phase][wave][row], 2 KB
  __shared__ float x_buf[2][TCH * XSTR];               // x chunks [t][row 0..31], 9.2 KB

  const int tid  = threadIdx.x;
  const int w    = tid >> 6;        // wave 0..7
  const int lane = tid & 63;
  const int r16  = lane & 15;
  const int q    = lane >> 4;
  const long base = (long)blockIdx.x * M_ROWS;

  for (int i = tid; i < 2 * GRPROWS * LDSW; i += NTHREADS) h_lds[0][i] = 0;  // h0 = 0 (both groups)

  // ---- stage z_j1 (gsel 0) and n_j1 (gsel 1) frags into LDS ----
  const int wz1b = ((w*2 + 0)*8)*512 + lane*8;
  const int wn1b = ((w*2 + 1)*8)*512 + lane*8;
#pragma unroll
  for (int gsel = 0; gsel < 2; ++gsel)
#pragma unroll
    for (int ks = 0; ks < 8; ++ks)
      *(short8*)&w_lds[((w*2 + gsel)*8 + ks)*512 + lane*8] =
        *(const short8*)&g_wsw[((((gsel + 1)*16 + w*2 + 1)*8 + ks)*64 + lane)*8];

  // ---- register-resident frags: r_j0, r_j1, z_j0, n_j0 (128 VGPR) ----
  short8 wrr0[8], wrr1[8], wrz0[8], wrn0[8];
#pragma unroll
  for (int ks = 0; ks < 8; ++ks) {
    wrr0[ks] = *(const short8*)&g_wsw[(((0*16 + w*2 + 0)*8 + ks)*64 + lane)*8];
    wrr1[ks] = *(const short8*)&g_wsw[(((0*16 + w*2 + 1)*8 + ks)*64 + lane)*8];
    wrz0[ks] = *(const short8*)&g_wsw[(((1*16 + w*2 + 0)*8 + ks)*64 + lane)*8];
    wrn0[ks] = *(const short8*)&g_wsw[(((2*16 + w*2 + 0)*8 + ks)*64 + lane)*8];
  }

  // per-lane constants for cols c(j) = w*32 + j*16 + r16, pre-scaled:
  // r,z: -log2e ; n: +2*log2e
  const float C1 = 1.44269504f;
  float swr[2], swz[2], swn[2], sbr[2], sbz[2], sbni[2], sbnh[2], wo[2];
  int hwb[2];
#pragma unroll
  for (int j = 0; j < 2; ++j) {
    int c = w*32 + j*16 + r16;
    hwb[j]   = (q*4)*LDSW + c;
    swr[j]   = -C1 * w_ih[c];
    swz[j]   = -C1 * w_ih[256 + c];
    swn[j]   = 2.0f * C1 * w_ih[512 + c];
    sbr[j]   = -C1 * (b_ih[c]       + b_hh[c]);
    sbz[j]   = -C1 * (b_ih[256 + c] + b_hh[256 + c]);
    sbni[j]  = 2.0f * C1 * b_ih[512 + c];
    sbnh[j]  = 2.0f * C1 * b_hh[512 + c];
    wo[j]    = w_out[c];
  }
  const float bo = b_out[0];
  const f32x4 zero4 = {0.f, 0.f, 0.f, 0.f};

  float hP[2][4], hQ[2][4];        // f32 h carry, both groups
#pragma unroll
  for (int j = 0; j < 2; ++j)
#pragma unroll
    for (int i = 0; i < 4; ++i) { hP[j][i] = 0.0f; hQ[j][i] = 0.0f; }

  const unsigned short* arP = &h_lds[0][r16*LDSW + q*8];
  const unsigned short* arQ = &h_lds[1][r16*LDSW + q*8];

  // x staging indices: thread -> (row = tid>>5 in 0..15, t-slot = tid&31)
  const int xrow = tid >> 5;
  const int xts  = tid & 31;

  // prefill x chunk 0 (both groups; coalesced 32-wide per row)
  x_buf[0][xts*XSTR + xrow]           = x[(base + xrow)*T_LEN + xts];
  x_buf[0][xts*XSTR + GRPROWS + xrow] = x[(base + GRPROWS + xrow)*T_LEN + xts];

  // acc sets: aP## built in A-intervals / consumed in B; aQ## vice versa
  f32x4 aP00, aP01, aP10, aP11, aP20, aP21;
  f32x4 aQ00, aQ01, aQ10, aQ11, aQ20, aQ21;

  // prefetch frags (transient; reloaded at each interval end)
  short8 pz0, pn0, pz1, pn1;

  barrier_lgkm();   // h zeros + w_lds + x chunk 0 staged

  WPREF

  // ---- pre-loop interval A0: MFMA(P, 0) only ----
  {
    ACCB(aP)
    KSTEPP(aP, arP, 0, pz0, pn0, )
    KSTEPP(aP, arP, 1, pz1, pn1, )
    KSTEP(aP, arP, 2, ) KSTEP(aP, arP, 3, ) KSTEP(aP, arP, 4, )
    KSTEP(aP, arP, 5, ) KSTEP(aP, arP, 6, ) KSTEP(aP, arP, 7, )
    WPREF
    barrier_lgkm();
  }

#pragma unroll 1
  for (int s = 0; s < T_LEN - 1; ++s) {     // s = 0..1022
    const int tr = s & (TCH - 1);
    const int tc = s >> 5;
    const int xp = tc & 1;
    const int refill = (tr == 1) && (tc + 1 < NCH);
    const int finB = ((s & 3) * 2) * 64;        // rotating FIN wave: 0,2,4,6
    const int finA = ((s & 3) * 2 + 1) * 64;    // rotating FIN wave: 1,3,5,7

    // ======== interval B(s): MFMA(Q,s) + gates(P,s) + fin(P,s-1) ========
    {
      // x refill: issue coalesced loads NOW, ds_write at interval end
      float xa, xb;
      if (refill) {
        const long t2 = (long)(tc + 1)*TCH + xts;
        xa = x[(base + xrow)*T_LEN + t2];
        xb = x[(base + GRPROWS + xrow)*T_LEN + t2];
      }
      f32x4 xvP; XREAD(xvP, 0, xp, tr)
      if (s > 0) { FIN(0, s-1, finB) }
      ACCB(aQ)
      f32x4 voP = zero4;
      KSTEPP(aQ, arQ, 0, pz0, pn0, GEL(aP, hP, xvP, voP, 0, 0))
      KSTEPP(aQ, arQ, 1, pz1, pn1, GEL(aP, hP, xvP, voP, 0, 1) PUBP(hP, 0, 0, 0))
      KSTEP(aQ, arQ, 2, GEL(aP, hP, xvP, voP, 0, 2))
      KSTEP(aQ, arQ, 3, GEL(aP, hP, xvP, voP, 0, 3) PUBP(hP, 0, 0, 2))
      KSTEP(aQ, arQ, 4, GEL(aP, hP, xvP, voP, 1, 0))
      KSTEP(aQ, arQ, 5, GEL(aP, hP, xvP, voP, 1, 1) PUBP(hP, 0, 1, 0))
      KSTEP(aQ, arQ, 6, GEL(aP, hP, xvP, voP, 1, 2))
      KSTEP(aQ, arQ, 7, GEL(aP, hP, xvP, voP, 1, 3) PUBP(hP, 0, 1, 2))
      VORED(voP, 0, s)
      if (refill) {
        x_buf[xp ^ 1][xts*XSTR + xrow]           = xa;
        x_buf[xp ^ 1][xts*XSTR + GRPROWS + xrow] = xb;
      }
      WPREF
      barrier_lgkm();
    }
    // ======== interval A(s+1): MFMA(P,s+1) + gates(Q,s) + fin(Q,s-1) ========
    {
      f32x4 xvQ; XREAD(xvQ, 1, xp, tr)
      if (s > 0) { FIN(1, s-1, finA) }
      ACCB(aP)
      f32x4 voQ = zero4;
      KSTEPP(aP, arP, 0, pz0, pn0, GEL(aQ, hQ, xvQ, voQ, 0, 0))
      KSTEPP(aP, arP, 1, pz1, pn1, GEL(aQ, hQ, xvQ, voQ, 0, 1) PUBP(hQ, 1, 0, 0))
      KSTEP(aP, arP, 2, GEL(aQ, hQ, xvQ, voQ, 0, 2))
      KSTEP(aP, arP, 3, GEL(aQ, hQ, xvQ, voQ, 0, 3) PUBP(hQ, 1, 0, 2))
      KSTEP(aP, arP, 4, GEL(aQ, hQ, xvQ, voQ, 1, 0))
      KSTEP(aP, arP, 5, GEL(aQ, hQ, xvQ, voQ, 1, 1) PUBP(hQ, 1, 1, 0))
      KSTEP(aP, arP, 6, GEL(aQ, hQ, xvQ, voQ, 1, 2))
      KSTEP(aP, arP, 7, GEL(aQ, hQ, xvQ, voQ, 1, 3) PUBP(hQ, 1, 1, 2))
      VORED(voQ, 1, s)
      WPREF
      barrier_lgkm();
    }
  }

  // ======== interval B(1023): MFMA(Q,1023) + gates(P,1023) + fin(P,1022) ========
  {
    const int s = T_LEN - 1;                 // tr=31, tc=31, xp=1
    f32x4 xvP; XREAD(xvP, 0, 1, TCH - 1)
    FIN(0, s-1, ((s & 3) * 2) * 64)
    ACCB(aQ)
    f32x4 voP = zero4;
    KSTEPP(aQ, arQ, 0, pz0, pn0, GEL(aP, hP, xvP, voP, 0, 0))
    KSTEPP(aQ, arQ, 1, pz1, pn1, GEL(aP, hP, xvP, voP, 0, 1) PUBP(hP, 0, 0, 0))
    KSTEP(aQ, arQ, 2, GEL(aP, hP, xvP, voP, 0, 2))
    KSTEP(aQ, arQ, 3, GEL(aP, hP, xvP, voP, 0, 3) PUBP(hP, 0, 0, 2))
    KSTEP(aQ, arQ, 4, GEL(aP, hP, xvP, voP, 1, 0))
    KSTEP(aQ, arQ, 5, GEL(aP, hP, xvP, voP, 1, 1) PUBP(hP, 0, 1, 0))
    KSTEP(aQ, arQ, 6, GEL(aP, hP, xvP, voP, 1, 2))
    KSTEP(aQ, arQ, 7, GEL(aP, hP, xvP, voP, 1, 3) PUBP(hP, 0, 1, 2))
    VORED(voP, 0, s)
    barrier_lgkm();
  }
  // ======== epilogue interval: gates(Q,1023) + fin(Q,1022) ========
  {
    const int s = T_LEN - 1;
    f32x4 xvQ; XREAD(xvQ, 1, 1, TCH - 1)
    FIN(1, s-1, ((s & 3) * 2 + 1) * 64)
    f32x4 voQ = zero4;
    GEL(aQ, hQ, xvQ, voQ, 0, 0)
    GEL(aQ, hQ, xvQ, voQ, 0, 1)
    GEL(aQ, hQ, xvQ, voQ, 0, 2)
    GEL(aQ, hQ, xvQ, voQ, 0, 3)
    GEL(aQ, hQ, xvQ, voQ, 1, 0)
    GEL(aQ, hQ, xvQ, voQ, 1, 1)
    GEL(aQ, hQ, xvQ, voQ, 1, 2)
    GEL(aQ, hQ, xvQ, voQ, 1, 3)
    VORED(voQ, 1, s)
    barrier_lgkm();
  }
  // ======== final finalizes: (P,1023) and (Q,1023) ========
  FIN(0, T_LEN - 1, 0)
  FIN(1, T_LEN - 1, 64)
}

extern "C" void kernel_launch(void* const* d_in, const int* in_sizes, int n_in,
                              void* d_out, int out_size, void* d_ws, size_t ws_size,
                              hipStream_t stream) {
  const float* x     = (const float*)d_in[0];
  const float* w_ih  = (const float*)d_in[1];
  const float* w_hh  = (const float*)d_in[2];
  const float* b_ih  = (const float*)d_in[3];
  const float* b_hh  = (const float*)d_in[4];
  const float* w_out = (const float*)d_in[5];
  const float* b_out = (const float*)d_in[6];
  float* out = (float*)d_out;

  prep_w<<<768, 256, 0, stream>>>(w_hh);
  gru_kernel<<<NBLOCKS, NTHREADS, 0, stream>>>(x, w_ih, b_ih, b_hh, w_out, b_out, out);
}

// Round 10
// 6633.109 us; speedup vs baseline: 1.2868x; 1.2413x over previous
//
#include <hip/hip_runtime.h>

// Persistent batched-GRU kernel for MI355X (gfx950), round 17 (resubmit;
// rounds 7 and 9 were GPUAcquisitionTimeouts, kernel never ran).
// r15 (+24 permanent VGPR) and r16 (+16 transient-across-barrier VGPR) BOTH
// spilled (WRITE_SIZE 214->890/730 MB) -> register margin over r14 is ZERO.
// This round: r14 base (7706us best) + register-NEUTRAL trims only:
//  (1) rotating FIN owner (scalar math only): B intervals use waves 0,2,4,6;
//      A intervals 1,3,5,7 -> straggler cost spread across waves.
//  (2) op layout transposed to [g][ph][row][12-pad] so FIN reads 2x
//      ds_read_b128 instead of 8x strided b32 (sum order preserved ->
//      bit-identical). LDS 159.2 -> 163.3 KB (under 163840 cap).
// Structural note: occupancy is pinned at 2 waves/SIMD by weight residency
// (384 KB = 256 KB regs + 128 KB LDS); that is the wall behind the 2.5x gap
// to the ~3.0ms MFMA floor. All bf16 re-balances hit it; fp8 weights would
// break it but risk absmax.
// Carried from r14: two-group pipeline (P/Q), diet gate math, bias-preloaded
// accs, cvt_pk publishes, x chunk staging via LDS, lgkm-only barrier.

#define B_TOTAL 16384
#define T_LEN   1024
#define GRPROWS 16
#define M_ROWS  32
#define NBLOCKS (B_TOTAL / M_ROWS)      // 512 blocks; 2 sequential per CU
#define NTHREADS 512                    // 8 waves
#define LDSW    264                     // h row stride in shorts
#define TCH     32                      // x chunk length (t steps)
#define NCH     (T_LEN / TCH)           // 32
#define XSTR    36                      // x_buf t-row stride in floats
#define OPW     12                      // op row stride in floats (48B, 16B-aligned)

typedef short short8 __attribute__((ext_vector_type(8)));
typedef float f32x4  __attribute__((ext_vector_type(4)));

__device__ unsigned short g_wsw[196608];   // swizzled, PRE-SCALED bf16 W_hh

__device__ __forceinline__ unsigned short f2b(float f) {
  unsigned u = __builtin_bit_cast(unsigned, f);
  u += 0x7fffu + ((u >> 16) & 1u);
  return (unsigned short)(u >> 16);
}
__device__ __forceinline__ unsigned cvt_pk_bf16(float lo, float hi) {
  unsigned r;
  asm("v_cvt_pk_bf16_f32 %0, %1, %2" : "=v"(r) : "v"(lo), "v"(hi));
  return r;
}
// sum over a 16-lane DPP row; result valid in the LAST lane (r16==15)
__device__ __forceinline__ float dpp_red16(float v) {
  int x = __builtin_bit_cast(int, v);
  v += __builtin_bit_cast(float, __builtin_amdgcn_update_dpp(0, x, 0x118, 0xF, 0xF, true)); // row_shr:8
  x = __builtin_bit_cast(int, v);
  v += __builtin_bit_cast(float, __builtin_amdgcn_update_dpp(0, x, 0x114, 0xF, 0xF, true)); // row_shr:4
  x = __builtin_bit_cast(int, v);
  v += __builtin_bit_cast(float, __builtin_amdgcn_update_dpp(0, x, 0x112, 0xF, 0xF, true)); // row_shr:2
  x = __builtin_bit_cast(int, v);
  v += __builtin_bit_cast(float, __builtin_amdgcn_update_dpp(0, x, 0x111, 0xF, 0xF, true)); // row_shr:1
  return v;
}
// barrier draining LDS only (no vmcnt(0): global stores stay in flight)
__device__ __forceinline__ void barrier_lgkm() {
  asm volatile("s_waitcnt lgkmcnt(0)\n\ts_barrier" ::: "memory");
}

// Swizzle W_hh (768x256 f32 row-major) into fragment-major bf16, PRE-SCALED:
// rows 0..511 (r,z) * -log2e ; rows 512..767 (n) * 2*log2e.
__global__ void prep_w(const float* __restrict__ w_hh) {
  int tid  = blockIdx.x * 256 + threadIdx.x;     // 196608 total
  int e    = tid & 7;
  int lane = (tid >> 3) & 63;
  int ks   = (tid >> 9) & 7;
  int nt   = tid >> 12;
  int row  = nt * 16 + (lane & 15);
  int col  = ks * 32 + (lane >> 4) * 8 + e;
  float s  = (row < 512) ? -1.44269504f : 2.88539008f;
  g_wsw[tid] = f2b(w_hh[row * 256 + col] * s);
}

#define MF(A, B, C) __builtin_amdgcn_mfma_f32_16x16x32_bf16((A), (B), (C), 0, 0, 0)

// one K-step for acc-set P## (6 chains): 4 register B-frags + 2 LDS B-frags,
// EXTRA = interleaved gate work for the other group
#define KSTEP(P, AR, KS, EXTRA)  {                                             \
    short8 a_  = *(const short8*)((AR) + (KS)*32);                             \
    short8 z1_ = *(const short8*)&w_lds[wz1b + (KS)*512];                      \
    short8 n1_ = *(const short8*)&w_lds[wn1b + (KS)*512];                      \
    P##00 = MF(a_, wrr0[KS], P##00);                                           \
    P##01 = MF(a_, wrr1[KS], P##01);                                           \
    P##10 = MF(a_, wrz0[KS], P##10);                                           \
    P##11 = MF(a_, z1_,      P##11);                                           \
    P##20 = MF(a_, wrn0[KS], P##20);                                           \
    P##21 = MF(a_, n1_,      P##21);                                           \
    EXTRA                                                                      \
  }

// one gate element, DIET math (accs carry fused scaled biases).
#define GEL(AC, HR, XV, VO, J, I) {                                            \
    float t_r = __builtin_fmaf(XV[I], swr[J], AC##0##J[I]);                    \
    float rg_ = __builtin_amdgcn_rcpf(1.0f + __builtin_amdgcn_exp2f(t_r));     \
    float t_z = __builtin_fmaf(XV[I], swz[J], AC##1##J[I]);                    \
    float zg_ = __builtin_amdgcn_rcpf(1.0f + __builtin_amdgcn_exp2f(t_z));     \
    float t_n = __builtin_fmaf(XV[I], swn[J], sbni[J]);                        \
    float yn_ = __builtin_fmaf(rg_, AC##2##J[I], t_n);                         \
    float rn_ = __builtin_amdgcn_rcpf(1.0f + __builtin_amdgcn_exp2f(yn_));     \
    float ng_ = __builtin_fmaf(-2.0f, rn_, 1.0f);                              \
    float hn_ = __builtin_fmaf(zg_, HR[J][I] - ng_, ng_);                      \
    HR[J][I] = hn_;                                                            \
    VO[I] += fmaxf(hn_, 0.0f)*wo[J];                                           \
  }

// publish rows (I0, I0+1) of column c(J) for group HG as a packed bf16 pair
#define PUBP(HR, HG, J, I0) {                                                  \
    unsigned pk_ = cvt_pk_bf16(HR[J][I0], HR[J][(I0)+1]);                      \
    h_lds[HG][hwb[J] + (I0)*LDSW]     = (unsigned short)pk_;                   \
    h_lds[HG][hwb[J] + ((I0)+1)*LDSW] = (unsigned short)(pk_ >> 16);           \
  }

// out-partial reduce + store into transposed op[row][wave] (lane 15 only)
#define VORED(VO, G, S) {                                                      \
    _Pragma("unroll") for (int i_ = 0; i_ < 4; ++i_) VO[i_] = dpp_red16(VO[i_]); \
    if (r16 == 15) {                                                           \
      _Pragma("unroll") for (int i_ = 0; i_ < 4; ++i_)                         \
        op[G][(S)&1][q*4 + i_][w] = VO[i_];                                    \
    } }

// finalize out(G, S): 16 threads starting at TLO; 2x ds_read_b128, sum in
// the SAME ww order as before (bit-identical), store
#define FIN(G, S, TLO)                                                         \
  if (tid >= (TLO) && tid < (TLO) + 16) {                                      \
    const float* pr_ = &op[G][(S)&1][tid - (TLO)][0];                          \
    f32x4 p0_ = *(const f32x4*)pr_;                                            \
    f32x4 p1_ = *(const f32x4*)(pr_ + 4);                                      \
    float o_ = bo + p0_[0] + p0_[1] + p0_[2] + p0_[3]                          \
                  + p1_[0] + p1_[1] + p1_[2] + p1_[3];                         \
    out[(base + (G)*GRPROWS + (tid - (TLO)))*T_LEN + (S)] = o_;                \
  }

// acc init: fused scaled biases (r in acc0, z in acc1, n-hh in acc2)
#define ACCB(P) {                                                              \
    P##00 = (f32x4){sbr[0],sbr[0],sbr[0],sbr[0]};                              \
    P##01 = (f32x4){sbr[1],sbr[1],sbr[1],sbr[1]};                              \
    P##10 = (f32x4){sbz[0],sbz[0],sbz[0],sbz[0]};                              \
    P##11 = (f32x4){sbz[1],sbz[1],sbz[1],sbz[1]};                              \
    P##20 = (f32x4){sbnh[0],sbnh[0],sbnh[0],sbnh[0]};                          \
    P##21 = (f32x4){sbnh[1],sbnh[1],sbnh[1],sbnh[1]};                          \
  }

// broadcast read of 4 x values for group G from x_buf (conflict-free)
#define XREAD(XV, G, XP, TR)                                                   \
  XV = *(const f32x4*)&x_buf[XP][(TR)*XSTR + (G)*GRPROWS + q*4];

__global__ __launch_bounds__(NTHREADS, 2) void gru_kernel(
    const float* __restrict__ x,
    const float* __restrict__ w_ih,
    const float* __restrict__ b_ih,
    const float* __restrict__ b_hh,
    const float* __restrict__ w_out,
    const float* __restrict__ b_out,
    float* __restrict__ out)
{
  __shared__ unsigned short h_lds[2][GRPROWS * LDSW];  // [group], 16.5 KB
  __shared__ unsigned short w_lds[16 * 8 * 512];       // z_j1/n_j1 frags, 128 KB
  __shared__ float op[2][2][GRPROWS][OPW];             // [group][phase][row][wave+pad], 6 KB
  __shared__ float x_buf[2][TCH * XSTR];               // x chunks [t][row 0..31], 9.2 KB

  const int tid  = threadIdx.x;
  const int w    = tid >> 6;        // wave 0..7
  const int lane = tid & 63;
  const int r16  = lane & 15;
  const int q    = lane >> 4;
  const long base = (long)blockIdx.x * M_ROWS;

  for (int i = tid; i < 2 * GRPROWS * LDSW; i += NTHREADS) h_lds[0][i] = 0;  // h0 = 0 (both groups)

  // ---- stage z_j1 (gsel 0) and n_j1 (gsel 1) frags into LDS ----
  const int wz1b = ((w*2 + 0)*8)*512 + lane*8;
  const int wn1b = ((w*2 + 1)*8)*512 + lane*8;
#pragma unroll
  for (int gsel = 0; gsel < 2; ++gsel)
#pragma unroll
    for (int ks = 0; ks < 8; ++ks)
      *(short8*)&w_lds[((w*2 + gsel)*8 + ks)*512 + lane*8] =
        *(const short8*)&g_wsw[((((gsel + 1)*16 + w*2 + 1)*8 + ks)*64 + lane)*8];

  // ---- register-resident frags: r_j0, r_j1, z_j0, n_j0 (128 VGPR) ----
  short8 wrr0[8], wrr1[8], wrz0[8], wrn0[8];
#pragma unroll
  for (int ks = 0; ks < 8; ++ks) {
    wrr0[ks] = *(const short8*)&g_wsw[(((0*16 + w*2 + 0)*8 + ks)*64 + lane)*8];
    wrr1[ks] = *(const short8*)&g_wsw[(((0*16 + w*2 + 1)*8 + ks)*64 + lane)*8];
    wrz0[ks] = *(const short8*)&g_wsw[(((1*16 + w*2 + 0)*8 + ks)*64 + lane)*8];
    wrn0[ks] = *(const short8*)&g_wsw[(((2*16 + w*2 + 0)*8 + ks)*64 + lane)*8];
  }

  // per-lane constants for cols c(j) = w*32 + j*16 + r16, pre-scaled:
  // r,z: -log2e ; n: +2*log2e
  const float C1 = 1.44269504f;
  float swr[2], swz[2], swn[2], sbr[2], sbz[2], sbni[2], sbnh[2], wo[2];
  int hwb[2];
#pragma unroll
  for (int j = 0; j < 2; ++j) {
    int c = w*32 + j*16 + r16;
    hwb[j]   = (q*4)*LDSW + c;
    swr[j]   = -C1 * w_ih[c];
    swz[j]   = -C1 * w_ih[256 + c];
    swn[j]   = 2.0f * C1 * w_ih[512 + c];
    sbr[j]   = -C1 * (b_ih[c]       + b_hh[c]);
    sbz[j]   = -C1 * (b_ih[256 + c] + b_hh[256 + c]);
    sbni[j]  = 2.0f * C1 * b_ih[512 + c];
    sbnh[j]  = 2.0f * C1 * b_hh[512 + c];
    wo[j]    = w_out[c];
  }
  const float bo = b_out[0];
  const f32x4 zero4 = {0.f, 0.f, 0.f, 0.f};

  float hP[2][4], hQ[2][4];        // f32 h carry, both groups
#pragma unroll
  for (int j = 0; j < 2; ++j)
#pragma unroll
    for (int i = 0; i < 4; ++i) { hP[j][i] = 0.0f; hQ[j][i] = 0.0f; }

  const unsigned short* arP = &h_lds[0][r16*LDSW + q*8];
  const unsigned short* arQ = &h_lds[1][r16*LDSW + q*8];

  // x staging indices: thread -> (row = tid>>5 in 0..15, t-slot = tid&31)
  const int xrow = tid >> 5;
  const int xts  = tid & 31;

  // prefill x chunk 0 (both groups; coalesced 32-wide per row)
  x_buf[0][xts*XSTR + xrow]           = x[(base + xrow)*T_LEN + xts];
  x_buf[0][xts*XSTR + GRPROWS + xrow] = x[(base + GRPROWS + xrow)*T_LEN + xts];

  // acc sets: aP## built in A-intervals / consumed in B; aQ## vice versa
  f32x4 aP00, aP01, aP10, aP11, aP20, aP21;
  f32x4 aQ00, aQ01, aQ10, aQ11, aQ20, aQ21;

  barrier_lgkm();   // h zeros + w_lds + x chunk 0 staged

  // ---- pre-loop interval A0: MFMA(P, 0) only ----
  {
    ACCB(aP)
    KSTEP(aP, arP, 0, ) KSTEP(aP, arP, 1, ) KSTEP(aP, arP, 2, ) KSTEP(aP, arP, 3, )
    KSTEP(aP, arP, 4, ) KSTEP(aP, arP, 5, ) KSTEP(aP, arP, 6, ) KSTEP(aP, arP, 7, )
    barrier_lgkm();
  }

#pragma unroll 1
  for (int s = 0; s < T_LEN - 1; ++s) {     // s = 0..1022
    const int tr = s & (TCH - 1);
    const int tc = s >> 5;
    const int xp = tc & 1;
    const int refill = (tr == 1) && (tc + 1 < NCH);
    const int finB = ((s & 3) * 2) * 64;        // rotating FIN wave: 0,2,4,6
    const int finA = ((s & 3) * 2 + 1) * 64;    // rotating FIN wave: 1,3,5,7

    // ======== interval B(s): MFMA(Q,s) + gates(P,s) + fin(P,s-1) ========
    {
      // x refill: issue coalesced loads NOW, ds_write at interval end
      float xa, xb;
      if (refill) {
        const long t2 = (long)(tc + 1)*TCH + xts;
        xa = x[(base + xrow)*T_LEN + t2];
        xb = x[(base + GRPROWS + xrow)*T_LEN + t2];
      }
      f32x4 xvP; XREAD(xvP, 0, xp, tr)
      if (s > 0) { FIN(0, s-1, finB) }
      ACCB(aQ)
      f32x4 voP = zero4;
      KSTEP(aQ, arQ, 0, GEL(aP, hP, xvP, voP, 0, 0))
      KSTEP(aQ, arQ, 1, GEL(aP, hP, xvP, voP, 0, 1) PUBP(hP, 0, 0, 0))
      KSTEP(aQ, arQ, 2, GEL(aP, hP, xvP, voP, 0, 2))
      KSTEP(aQ, arQ, 3, GEL(aP, hP, xvP, voP, 0, 3) PUBP(hP, 0, 0, 2))
      KSTEP(aQ, arQ, 4, GEL(aP, hP, xvP, voP, 1, 0))
      KSTEP(aQ, arQ, 5, GEL(aP, hP, xvP, voP, 1, 1) PUBP(hP, 0, 1, 0))
      KSTEP(aQ, arQ, 6, GEL(aP, hP, xvP, voP, 1, 2))
      KSTEP(aQ, arQ, 7, GEL(aP, hP, xvP, voP, 1, 3) PUBP(hP, 0, 1, 2))
      VORED(voP, 0, s)
      if (refill) {
        x_buf[xp ^ 1][xts*XSTR + xrow]           = xa;
        x_buf[xp ^ 1][xts*XSTR + GRPROWS + xrow] = xb;
      }
      barrier_lgkm();
    }
    // ======== interval A(s+1): MFMA(P,s+1) + gates(Q,s) + fin(Q,s-1) ========
    {
      f32x4 xvQ; XREAD(xvQ, 1, xp, tr)
      if (s > 0) { FIN(1, s-1, finA) }
      ACCB(aP)
      f32x4 voQ = zero4;
      KSTEP(aP, arP, 0, GEL(aQ, hQ, xvQ, voQ, 0, 0))
      KSTEP(aP, arP, 1, GEL(aQ, hQ, xvQ, voQ, 0, 1) PUBP(hQ, 1, 0, 0))
      KSTEP(aP, arP, 2, GEL(aQ, hQ, xvQ, voQ, 0, 2))
      KSTEP(aP, arP, 3, GEL(aQ, hQ, xvQ, voQ, 0, 3) PUBP(hQ, 1, 0, 2))
      KSTEP(aP, arP, 4, GEL(aQ, hQ, xvQ, voQ, 1, 0))
      KSTEP(aP, arP, 5, GEL(aQ, hQ, xvQ, voQ, 1, 1) PUBP(hQ, 1, 1, 0))
      KSTEP(aP, arP, 6, GEL(aQ, hQ, xvQ, voQ, 1, 2))
      KSTEP(aP, arP, 7, GEL(aQ, hQ, xvQ, voQ, 1, 3) PUBP(hQ, 1, 1, 2))
      VORED(voQ, 1, s)
      barrier_lgkm();
    }
  }

  // ======== interval B(1023): MFMA(Q,1023) + gates(P,1023) + fin(P,1022) ========
  {
    const int s = T_LEN - 1;                 // tr=31, tc=31, xp=1
    f32x4 xvP; XREAD(xvP, 0, 1, TCH - 1)
    FIN(0, s-1, ((s & 3) * 2) * 64)
    ACCB(aQ)
    f32x4 voP = zero4;
    KSTEP(aQ, arQ, 0, GEL(aP, hP, xvP, voP, 0, 0))
    KSTEP(aQ, arQ, 1, GEL(aP, hP, xvP, voP, 0, 1) PUBP(hP, 0, 0, 0))
    KSTEP(aQ, arQ, 2, GEL(aP, hP, xvP, voP, 0, 2))
    KSTEP(aQ, arQ, 3, GEL(aP, hP, xvP, voP, 0, 3) PUBP(hP, 0, 0, 2))
    KSTEP(aQ, arQ, 4, GEL(aP, hP, xvP, voP, 1, 0))
    KSTEP(aQ, arQ, 5, GEL(aP, hP, xvP, voP, 1, 1) PUBP(hP, 0, 1, 0))
    KSTEP(aQ, arQ, 6, GEL(aP, hP, xvP, voP, 1, 2))
    KSTEP(aQ, arQ, 7, GEL(aP, hP, xvP, voP, 1, 3) PUBP(hP, 0, 1, 2))
    VORED(voP, 0, s)
    barrier_lgkm();
  }
  // ======== epilogue interval: gates(Q,1023) + fin(Q,1022) ========
  {
    const int s = T_LEN - 1;
    f32x4 xvQ; XREAD(xvQ, 1, 1, TCH - 1)
    FIN(1, s-1, ((s & 3) * 2 + 1) * 64)
    f32x4 voQ = zero4;
    GEL(aQ, hQ, xvQ, voQ, 0, 0)
    GEL(aQ, hQ, xvQ, voQ, 0, 1)
    GEL(aQ, hQ, xvQ, voQ, 0, 2)
    GEL(aQ, hQ, xvQ, voQ, 0, 3)
    GEL(aQ, hQ, xvQ, voQ, 1, 0)
    GEL(aQ, hQ, xvQ, voQ, 1, 1)
    GEL(aQ, hQ, xvQ, voQ, 1, 2)
    GEL(aQ, hQ, xvQ, voQ, 1, 3)
    VORED(voQ, 1, s)
    barrier_lgkm();
  }
  // ======== final finalizes: (P,1023) and (Q,1023) ========
  FIN(0, T_LEN - 1, 0)
  FIN(1, T_LEN - 1, 64)
}

extern "C" void kernel_launch(void* const* d_in, const int* in_sizes, int n_in,
                              void* d_out, int out_size, void* d_ws, size_t ws_size,
                              hipStream_t stream) {
  const float* x     = (const float*)d_in[0];
  const float* w_ih  = (const float*)d_in[1];
  const float* w_hh  = (const float*)d_in[2];
  const float* b_ih  = (const float*)d_in[3];
  const float* b_hh  = (const float*)d_in[4];
  const float* w_out = (const float*)d_in[5];
  const float* b_out = (const float*)d_in[6];
  float* out = (float*)d_out;

  prep_w<<<768, 256, 0, stream>>>(w_hh);
  gru_kernel<<<NBLOCKS, NTHREADS, 0, stream>>>(x, w_ih, b_ih, b_hh, w_out, b_out, out);
}